// Round 7
// baseline (1408.687 us; speedup 1.0000x reference)
//
#include <hip/hip_runtime.h>
#include <hip/hip_bf16.h>
#include <math.h>

#define L_TOK 1569
#define DM 192
#define DI 384
#define DS 16
#define DTR 12
#define DCONV 4
#define XDBL_N (DTR + 2*DS)   // 44
#define DEPTH 8
#define NCHUNK 25
#define CLEN 64
#define NPATCH 1568
#define NDG 24                // d-groups (384/16)

typedef __attribute__((ext_vector_type(8))) short short8;
typedef __attribute__((ext_vector_type(4))) float f32x4;

__device__ __forceinline__ unsigned short f2bf(float f) {
  unsigned int u = __float_as_uint(f);
  u += 0x7FFFu + ((u >> 16) & 1u);   // round-to-nearest-even
  return (unsigned short)(u >> 16);
}

// ---------------------------------------------------------------------------
// im2col + cur init.
// ---------------------------------------------------------------------------
__global__ __launch_bounds__(256) void im2col_kernel(
    const float* __restrict__ x, const float* __restrict__ cls,
    const float* __restrict__ pb, const float* __restrict__ pos,
    float* __restrict__ px, float* __restrict__ curp) {
  int gid = blockIdx.x * 256 + threadIdx.x;
  const int initN = (L_TOK * DM) / 4;   // 75312 float4s
  if (gid < initN) {
    int e4 = gid * 4;
    int tok = e4 / DM;
    int col = e4 % DM;
    float4 pv = *(const float4*)(pos + e4);
    float4 av = (tok == 0) ? *(const float4*)(cls + col)
                           : *(const float4*)(pb + col);
    float4 o = {pv.x + av.x, pv.y + av.y, pv.z + av.z, pv.w + av.w};
    *(float4*)(curp + e4) = o;
  }
  if (gid >= NPATCH * 192) return;      // 192 float4 per patch
  int patch = gid / 192;
  int r = gid % 192;
  int c = r / 64;
  int p = (r >> 2) & 15;
  int q = (r & 3) * 4;
  int t = patch / 196, hw = patch % 196, hh = hw / 14, w = hw % 14;
  const float* src = x + ((size_t)(c*8 + t)*224 + hh*16 + p)*224 + w*16 + q;
  *(float4*)(px + (size_t)patch*768 + r*4) = *(const float4*)src;
}

// ---------------------------------------------------------------------------
// Final LayerNorm over 192 features. One wave per token, 3 elems/lane.
// ---------------------------------------------------------------------------
__global__ __launch_bounds__(64) void ln_kernel(
    const float* __restrict__ in, float* __restrict__ out,
    const float* __restrict__ g, const float* __restrict__ b) {
  int tokn = blockIdx.x;
  int lane = threadIdx.x;
  const float* row = in + (size_t)tokn*DM;
  float x0 = row[lane], x1 = row[lane+64], x2 = row[lane+128];
  float s = x0 + x1 + x2;
  float s2 = x0*x0 + x1*x1 + x2*x2;
#pragma unroll
  for (int off = 1; off < 64; off <<= 1) {
    s  += __shfl_xor(s,  off, 64);
    s2 += __shfl_xor(s2, off, 64);
  }
  float m = s * (1.0f/192.0f);
  float v = s2 * (1.0f/192.0f) - m*m;
  float rs = rsqrtf(v + 1e-5f);
  float* orow = out + (size_t)tokn*DM;
  orow[lane]     = (x0 - m)*rs*g[lane]     + b[lane];
  orow[lane+64]  = (x1 - m)*rs*g[lane+64]  + b[lane+64];
  orow[lane+128] = (x2 - m)*rs*g[lane+128] + b[lane+128];
}

// ---------------------------------------------------------------------------
// Fused LN + xz GEMM (K=192 fully in LDS, one barrier before 6 MFMA k-steps).
// blockIdx.x==0 blocks zero xdbl rows; (1,0) block zeroes the scan flags.
// ---------------------------------------------------------------------------
__global__ __launch_bounds__(256) void lnxz_kernel(
    const float* __restrict__ cur, const float* __restrict__ g,
    const float* __restrict__ b, const float* __restrict__ W,
    float* __restrict__ xz, float* __restrict__ xdbl_z,
    int* __restrict__ flags) {
  __shared__ unsigned short As[64][200];
  __shared__ unsigned short Bs[64][200];
  __shared__ float gs[192], bs2[192];
  int tid = threadIdx.x;
  int m0 = blockIdx.y * 64, n0 = blockIdx.x * 64;
  int wave = tid >> 6, lane = tid & 63;
  int wr = wave >> 1, wc = wave & 1;
  int l15 = lane & 15, lk = (lane >> 4) * 8;

  for (int i = tid; i < 192; i += 256) { gs[i] = g[i]; bs2[i] = b[i]; }

  if (blockIdx.x == 0) {
    for (int i = tid; i < 64*11; i += 256) {
      int r = i / 11, q = i % 11;
      int row = m0 + r;
      if (row < L_TOK) {
        float4 z = {0.f,0.f,0.f,0.f};
        *(float4*)(xdbl_z + (size_t)row*XDBL_N + q*4) = z;
      }
    }
  }
  if (blockIdx.x == 1 && blockIdx.y == 0) {
    for (int i = tid; i < NDG*NCHUNK; i += 256) flags[i] = 0;
  }

  int r = tid >> 2, c0 = (tid & 3) * 48;
  float v[48];
  {
    int row = m0 + r;
    if (row < L_TOK) {
      const float* rp = cur + (size_t)row*DM + c0;
#pragma unroll
      for (int j = 0; j < 12; ++j) {
        float4 t4 = *(const float4*)(rp + j*4);
        v[j*4+0]=t4.x; v[j*4+1]=t4.y; v[j*4+2]=t4.z; v[j*4+3]=t4.w;
      }
    } else {
#pragma unroll
      for (int j = 0; j < 48; ++j) v[j] = 0.f;
    }
  }
  float s = 0.f, s2 = 0.f;
#pragma unroll
  for (int j = 0; j < 48; ++j) { s += v[j]; s2 += v[j]*v[j]; }
  s  += __shfl_xor(s, 1, 64); s2 += __shfl_xor(s2, 1, 64);
  s  += __shfl_xor(s, 2, 64); s2 += __shfl_xor(s2, 2, 64);
  float mu = s * (1.0f/192.0f);
  float var = s2 * (1.0f/192.0f) - mu*mu;
  float rsd = rsqrtf(var + 1e-5f);

  __syncthreads();   // gs/bs2 ready
#pragma unroll
  for (int j = 0; j < 48; ++j) {
    int k = c0 + j;
    As[r][k] = f2bf((v[j] - mu)*rsd*gs[k] + bs2[k]);
  }
  {
    const float* rp = W + (size_t)(n0 + r)*DM + c0;
#pragma unroll
    for (int j = 0; j < 12; ++j) {
      float4 t4 = *(const float4*)(rp + j*4);
      Bs[r][c0+j*4+0]=f2bf(t4.x); Bs[r][c0+j*4+1]=f2bf(t4.y);
      Bs[r][c0+j*4+2]=f2bf(t4.z); Bs[r][c0+j*4+3]=f2bf(t4.w);
    }
  }
  __syncthreads();

  f32x4 acc[2][2];
#pragma unroll
  for (int i = 0; i < 2; ++i)
#pragma unroll
    for (int j = 0; j < 2; ++j) acc[i][j] = (f32x4){0.f,0.f,0.f,0.f};

#pragma unroll
  for (int kk = 0; kk < 6; ++kk) {
    short8 af0 = *(const short8*)&As[wr*32      + l15][kk*32 + lk];
    short8 af1 = *(const short8*)&As[wr*32 + 16 + l15][kk*32 + lk];
    short8 bf0 = *(const short8*)&Bs[wc*32      + l15][kk*32 + lk];
    short8 bf1 = *(const short8*)&Bs[wc*32 + 16 + l15][kk*32 + lk];
    acc[0][0] = __builtin_amdgcn_mfma_f32_16x16x32_bf16(af0, bf0, acc[0][0], 0, 0, 0);
    acc[0][1] = __builtin_amdgcn_mfma_f32_16x16x32_bf16(af0, bf1, acc[0][1], 0, 0, 0);
    acc[1][0] = __builtin_amdgcn_mfma_f32_16x16x32_bf16(af1, bf0, acc[1][0], 0, 0, 0);
    acc[1][1] = __builtin_amdgcn_mfma_f32_16x16x32_bf16(af1, bf1, acc[1][1], 0, 0, 0);
  }

#pragma unroll
  for (int rr = 0; rr < 2; ++rr) {
#pragma unroll
    for (int cc = 0; cc < 2; ++cc) {
      int col = n0 + wc*32 + cc*16 + l15;
      int rowb = m0 + wr*32 + rr*16 + (lane >> 4)*4;
#pragma unroll
      for (int j = 0; j < 4; ++j) {
        int row = rowb + j;
        if (row < L_TOK) xz[(size_t)row*(2*DI) + col] = acc[rr][cc][j];
      }
    }
  }
}

// ---------------------------------------------------------------------------
// MFMA bf16 GEMM with split-K (patch embed + out projection).
// ---------------------------------------------------------------------------
__global__ __launch_bounds__(256) void mgemm_kernel(
    const float* __restrict__ A, int lda,
    const float* __restrict__ B, int ldb,
    float* __restrict__ C, int ldc,
    int M, int N, int ksl, int atomic) {
  __shared__ unsigned short As[64*40];
  __shared__ unsigned short Bs[64*40];
  int tid = threadIdx.x;
  int m0 = blockIdx.y * 64, n0 = blockIdx.x * 64;
  int kbase = blockIdx.z * ksl;
  int wave = tid >> 6, lane = tid & 63;
  int wr = wave >> 1, wc = wave & 1;
  int srow = tid >> 2;          // 0..63
  int skq  = (tid & 3) * 8;     // 0,8,16,24
  f32x4 acc[2][2];
#pragma unroll
  for (int i = 0; i < 2; ++i)
#pragma unroll
    for (int j = 0; j < 2; ++j) acc[i][j] = (f32x4){0.f,0.f,0.f,0.f};

  int am = m0 + srow;
  int bn = n0 + srow;
  bool a_ok = (am < M), b_ok = (bn < N);
  const float* ap = A + (size_t)am*lda + kbase + skq;
  const float* bp = B + (size_t)bn*ldb + kbase + skq;
  const float4 z4 = {0.f,0.f,0.f,0.f};
  int l15 = lane & 15, lk = (lane >> 4) * 8;

  int nt = ksl >> 5;
  float4 a0 = a_ok ? *(const float4*)(ap)     : z4;
  float4 a1 = a_ok ? *(const float4*)(ap + 4) : z4;
  float4 b0 = b_ok ? *(const float4*)(bp)     : z4;
  float4 b1 = b_ok ? *(const float4*)(bp + 4) : z4;

  for (int i = 0; i < nt; ++i) {
    {
      short8 pa, pb;
      pa[0]=f2bf(a0.x); pa[1]=f2bf(a0.y); pa[2]=f2bf(a0.z); pa[3]=f2bf(a0.w);
      pa[4]=f2bf(a1.x); pa[5]=f2bf(a1.y); pa[6]=f2bf(a1.z); pa[7]=f2bf(a1.w);
      pb[0]=f2bf(b0.x); pb[1]=f2bf(b0.y); pb[2]=f2bf(b0.z); pb[3]=f2bf(b0.w);
      pb[4]=f2bf(b1.x); pb[5]=f2bf(b1.y); pb[6]=f2bf(b1.z); pb[7]=f2bf(b1.w);
      *(short8*)&As[srow*40 + skq] = pa;
      *(short8*)&Bs[srow*40 + skq] = pb;
    }
    __syncthreads();
    bool pf = (i + 1 < nt);
    int k0n = (i + 1) << 5;
    a0 = (pf && a_ok) ? *(const float4*)(ap + k0n)     : z4;
    a1 = (pf && a_ok) ? *(const float4*)(ap + k0n + 4) : z4;
    b0 = (pf && b_ok) ? *(const float4*)(bp + k0n)     : z4;
    b1 = (pf && b_ok) ? *(const float4*)(bp + k0n + 4) : z4;

    short8 af0 = *(const short8*)&As[(wr*32      + l15)*40 + lk];
    short8 af1 = *(const short8*)&As[(wr*32 + 16 + l15)*40 + lk];
    short8 bf0 = *(const short8*)&Bs[(wc*32      + l15)*40 + lk];
    short8 bf1 = *(const short8*)&Bs[(wc*32 + 16 + l15)*40 + lk];
    acc[0][0] = __builtin_amdgcn_mfma_f32_16x16x32_bf16(af0, bf0, acc[0][0], 0, 0, 0);
    acc[0][1] = __builtin_amdgcn_mfma_f32_16x16x32_bf16(af0, bf1, acc[0][1], 0, 0, 0);
    acc[1][0] = __builtin_amdgcn_mfma_f32_16x16x32_bf16(af1, bf0, acc[1][0], 0, 0, 0);
    acc[1][1] = __builtin_amdgcn_mfma_f32_16x16x32_bf16(af1, bf1, acc[1][1], 0, 0, 0);
    __syncthreads();
  }

#pragma unroll
  for (int r = 0; r < 2; ++r) {
#pragma unroll
    for (int c = 0; c < 2; ++c) {
      int col = n0 + wc*32 + c*16 + l15;
      if (col >= N) continue;
      int rowb = m0 + wr*32 + r*16 + (lane >> 4)*4;
#pragma unroll
      for (int j = 0; j < 4; ++j) {
        int row = rowb + j;
        if (row >= M) continue;
        float v = acc[r][c][j];
        float* cp = C + (size_t)row*ldc + col;
        if (atomic) atomicAdd(cp, v);
        else        *cp = v;
      }
    }
  }
}

// ---------------------------------------------------------------------------
// xdbl GEMM, conv+SiLU fused in A-staging; split-K 12 (ksl=32, one k-step).
// Also exports u = silu(conv(xz)) to uc (fp32) for the scan.
// grid = (1, 25, 12). C zero-initialized by lnxz.
// ---------------------------------------------------------------------------
__global__ __launch_bounds__(256) void cgemm_kernel(
    const float* __restrict__ xz,
    const float* __restrict__ Wc, const float* __restrict__ bc,
    const float* __restrict__ B, float* __restrict__ C,
    float* __restrict__ uc) {
  __shared__ unsigned short As[64*40];
  __shared__ unsigned short Bs[64*40];
  __shared__ float wcs[32][4];
  __shared__ float bcs[32];
  const int M = L_TOK, N = XDBL_N;
  int tid = threadIdx.x;
  int m0 = blockIdx.y * 64;
  int kbase = blockIdx.z * 32;
  int wave = tid >> 6, lane = tid & 63;
  int wr = wave >> 1, wcq = wave & 1;
  int srow = tid >> 2;
  int skq  = (tid & 3) * 8;
  if (tid < 32) {
    *(float4*)wcs[tid] = *(const float4*)(Wc + (size_t)(kbase + tid)*4);
    bcs[tid] = bc[kbase + tid];
  }

  int t = m0 + srow;
  bool a_ok = (t < M);
  bool b_ok = (srow < N);
  const float* bp = B + (size_t)srow*DI + kbase + skq;
  const float4 z4 = {0.f,0.f,0.f,0.f};
  int l15 = lane & 15, lk = (lane >> 4) * 8;
  int cg = kbase + skq;

  float tap[4][8];
#pragma unroll
  for (int j = 0; j < 4; ++j) {
    int ts = t - 3 + j;
    float4 v0 = z4, v1 = z4;
    if (a_ok && ts >= 0) {
      v0 = *(const float4*)(xz + (size_t)ts*(2*DI) + cg);
      v1 = *(const float4*)(xz + (size_t)ts*(2*DI) + cg + 4);
    }
    tap[j][0]=v0.x; tap[j][1]=v0.y; tap[j][2]=v0.z; tap[j][3]=v0.w;
    tap[j][4]=v1.x; tap[j][5]=v1.y; tap[j][6]=v1.z; tap[j][7]=v1.w;
  }
  float4 bv0 = b_ok ? *(const float4*)(bp)     : z4;
  float4 bv1 = b_ok ? *(const float4*)(bp + 4) : z4;
  __syncthreads();   // wcs/bcs ready

  float uv[8];
  short8 pa, pb;
#pragma unroll
  for (int c = 0; c < 8; ++c) {
    float u = bcs[skq + c];
#pragma unroll
    for (int j = 0; j < 4; ++j) u = fmaf(tap[j][c], wcs[skq + c][j], u);
    u = u / (1.0f + expf(-u));
    uv[c] = u;
    pa[c] = (short)f2bf(u);
  }
  if (a_ok) {
    float4 o0 = {uv[0], uv[1], uv[2], uv[3]};
    float4 o1 = {uv[4], uv[5], uv[6], uv[7]};
    *(float4*)(uc + (size_t)t*DI + cg)     = o0;
    *(float4*)(uc + (size_t)t*DI + cg + 4) = o1;
  }
  pb[0]=f2bf(bv0.x); pb[1]=f2bf(bv0.y); pb[2]=f2bf(bv0.z); pb[3]=f2bf(bv0.w);
  pb[4]=f2bf(bv1.x); pb[5]=f2bf(bv1.y); pb[6]=f2bf(bv1.z); pb[7]=f2bf(bv1.w);
  *(short8*)&As[srow*40 + skq] = pa;
  *(short8*)&Bs[srow*40 + skq] = pb;
  __syncthreads();

  f32x4 acc[2][2];
#pragma unroll
  for (int i = 0; i < 2; ++i)
#pragma unroll
    for (int j = 0; j < 2; ++j) acc[i][j] = (f32x4){0.f,0.f,0.f,0.f};
  short8 af0 = *(const short8*)&As[(wr*32      + l15)*40 + lk];
  short8 af1 = *(const short8*)&As[(wr*32 + 16 + l15)*40 + lk];
  short8 bf0 = *(const short8*)&Bs[(wcq*32      + l15)*40 + lk];
  short8 bf1 = *(const short8*)&Bs[(wcq*32 + 16 + l15)*40 + lk];
  acc[0][0] = __builtin_amdgcn_mfma_f32_16x16x32_bf16(af0, bf0, acc[0][0], 0, 0, 0);
  acc[0][1] = __builtin_amdgcn_mfma_f32_16x16x32_bf16(af0, bf1, acc[0][1], 0, 0, 0);
  acc[1][0] = __builtin_amdgcn_mfma_f32_16x16x32_bf16(af1, bf0, acc[1][0], 0, 0, 0);
  acc[1][1] = __builtin_amdgcn_mfma_f32_16x16x32_bf16(af1, bf1, acc[1][1], 0, 0, 0);

#pragma unroll
  for (int r = 0; r < 2; ++r) {
#pragma unroll
    for (int c = 0; c < 2; ++c) {
      int col = wcq*32 + c*16 + l15;
      if (col >= N) continue;
      int rowb = m0 + wr*32 + r*16 + (lane >> 4)*4;
#pragma unroll
      for (int j = 0; j < 4; ++j) {
        int row = rowb + j;
        if (row >= M) continue;
        atomicAdd(C + (size_t)row*XDBL_N + col, acc[r][c][j]);
      }
    }
  }
}

// ---------------------------------------------------------------------------
// Fused selective scan (p1+carry+p3 in one kernel, decoupled lookback).
// grid = (NDG=24 d-groups, NCHUNK=25 chunks), 256 thr = 16d x 16n.
// Stage once; local scan from 0; publish (P,S) + flag; wait predecessor
// flags (blocks publish before waiting -> no chain); combine; emit y.
// ---------------------------------------------------------------------------
__global__ __launch_bounds__(256) void scan_fused(
    const float* __restrict__ uc, const float* __restrict__ xdbl,
    const float* __restrict__ xz,
    const float* __restrict__ W_dt, const float* __restrict__ b_dt,
    const float* __restrict__ A_log, const float* __restrict__ Dp,
    float* __restrict__ cP, float* __restrict__ cS,
    int* __restrict__ flags, float* __restrict__ yy) {
  __shared__ float us[CLEN][16], ds[CLEN][16], bs[CLEN][16];
  __shared__ float cs[CLEN][16], zs[CLEN][16];
  __shared__ float xd12[CLEN][12], wdt[16][12], bds[16];
  int tid = threadIdx.x;
  int dl = tid >> 4, n = tid & 15;
  int g = blockIdx.x;
  int d0 = g * 16;
  int cidx = blockIdx.y;
  int t0 = cidx * CLEN;
  int nt = min(CLEN, L_TOK - t0);

  for (int i = tid; i < CLEN*16; i += 256) {
    int tt = i >> 4, dd = i & 15;
    int t = t0 + tt;
    bool ok = (t < L_TOK);
    us[tt][dd] = ok ? uc[(size_t)t*DI + d0 + dd] : 0.0f;
    zs[tt][dd] = ok ? xz[(size_t)t*(2*DI) + DI + d0 + dd] : 0.0f;
  }
  for (int i = tid; i < CLEN*XDBL_N; i += 256) {
    int tt = i / XDBL_N, c = i % XDBL_N;
    int t = t0 + tt;
    float v = (t < L_TOK) ? xdbl[(size_t)t*XDBL_N + c] : 0.0f;
    if (c < 12) xd12[tt][c] = v;
    else if (c < 28) bs[tt][c-12] = v;
    else cs[tt][c-28] = v;
  }
  if (tid < 192) wdt[tid/12][tid%12] = W_dt[(d0 + tid/12)*DTR + tid%12];
  if (tid < 16)  bds[tid] = b_dt[d0+tid];
  __syncthreads();
  for (int i = tid; i < CLEN*16; i += 256) {
    int tt = i >> 4, dd = i & 15;
    float v = bds[dd];
#pragma unroll
    for (int r = 0; r < 12; ++r) v = fmaf(xd12[tt][r], wdt[dd][r], v);
    ds[tt][dd] = (v > 20.0f) ? v : log1pf(expf(v));
  }
  __syncthreads();

  int d = d0 + dl;
  float a2 = -expf(A_log[d*DS + n]) * 1.44269504088896340736f;

  // local scan from zero state
  float s = 0.0f, P = 1.0f;
  for (int tt = 0; tt < nt; ++tt) {
    float dlt = ds[tt][dl];
    float dA = exp2f(dlt * a2);
    s = fmaf(dA, s, dlt * bs[tt][n] * us[tt][dl]);
    P *= dA;
  }
  int o = (cidx * DI + d) * DS + n;
  cP[o] = P;
  cS[o] = s;
  __syncthreads();          // all stores drained (waitcnt before barrier)
  __threadfence();          // device-scope release
  if (tid == 0) atomicExch(&flags[g*NCHUNK + cidx], 1);

  // wait for all predecessor chunks of this d-group
  if (tid == 0) {
    for (int c2 = 0; c2 < cidx; ++c2) {
      while (atomicAdd(&flags[g*NCHUNK + c2], 0) == 0)
        __builtin_amdgcn_s_sleep(2);
    }
  }
  __syncthreads();
  __threadfence();          // device-scope acquire

  // carry-in = scan over predecessors' local (P,S)
  float sc = 0.0f;
  {
    int oo = d * DS + n;
    for (int c2 = 0; c2 < cidx; ++c2) {
      sc = fmaf(cP[(size_t)c2*(DI*DS) + oo], sc, cS[(size_t)c2*(DI*DS) + oo]);
    }
  }

  // emission with correct carry
  float dpv = Dp[d];
  s = sc;
  for (int tt = 0; tt < nt; ++tt) {
    float dlt = ds[tt][dl], uu = us[tt][dl];
    float dA = exp2f(dlt * a2);
    s = fmaf(dA, s, dlt * bs[tt][n] * uu);
    float p = s * cs[tt][n];
    p += __shfl_xor(p, 1, 64);
    p += __shfl_xor(p, 2, 64);
    p += __shfl_xor(p, 4, 64);
    p += __shfl_xor(p, 8, 64);
    if (n == 0) {
      float z = zs[tt][dl];
      float y = fmaf(uu, dpv, p);
      y *= z / (1.0f + expf(-z));
      yy[(size_t)(t0 + tt)*DI + d] = y;
    }
  }
}

// ---------------------------------------------------------------------------
extern "C" void kernel_launch(void* const* d_in, const int* in_sizes, int n_in,
                              void* d_out, int out_size, void* d_ws, size_t ws_size,
                              hipStream_t stream) {
  const float* x       = (const float*)d_in[0];
  const float* patch_w = (const float*)d_in[1];
  const float* patch_b = (const float*)d_in[2];
  const float* cls_tok = (const float*)d_in[3];
  const float* pos_emb = (const float*)d_in[4];
  const float* ln_g    = (const float*)d_in[5];
  const float* ln_b    = (const float*)d_in[6];
  const float* W_in    = (const float*)d_in[7];
  const float* Wc      = (const float*)d_in[8];
  const float* bc      = (const float*)d_in[9];
  const float* Wx      = (const float*)d_in[10];
  const float* W_dt    = (const float*)d_in[11];
  const float* b_dt    = (const float*)d_in[12];
  const float* A_log   = (const float*)d_in[13];
  const float* Dp      = (const float*)d_in[14];
  const float* W_out   = (const float*)d_in[15];
  const float* fn_g    = (const float*)d_in[16];
  const float* fn_b    = (const float*)d_in[17];

  float* ws = (float*)d_ws;
  float* cur   = ws;                       // 1569*192
  float* xz    = cur   + L_TOK*DM;         // 1569*768 (aliases px)
  float* xdbl  = xz    + L_TOK*2*DI;       // 1569*44
  float* yy    = xdbl  + L_TOK*XDBL_N;     // 1569*384
  float* uc    = yy    + L_TOK*DI;         // 1569*384
  float* cP    = uc    + L_TOK*DI;         // 25*6144
  float* cS    = cP    + NCHUNK*DI*DS;
  int*   flags = (int*)(cS + NCHUNK*DI*DS);// 24*25 ints
  float* px    = xz;                       // im2col buffer, dead before layer 0's xz

  // im2col + cur init (pos + bias/cls)
  im2col_kernel<<<(NPATCH*192 + 255)/256, 256, 0, stream>>>(
      x, cls_tok, patch_b, pos_emb, px, cur);
  // patch GEMM: cur[1..] += px @ patch_w^T, M=1568, N=192, K=768, split-K 4
  {
    dim3 grid(DM/64, (NPATCH + 63)/64, 4);
    mgemm_kernel<<<grid, 256, 0, stream>>>(px, 768, patch_w, 768, cur + DM, DM,
                                           NPATCH, DM, 768/4, 1);
  }

  for (int dep = 0; dep < DEPTH; ++dep) {
    const float* g     = ln_g  + dep*DM;
    const float* bb    = ln_b  + dep*DM;
    const float* Win_l = W_in  + (size_t)dep*2*DI*DM;
    const float* Wc_l  = Wc    + (size_t)dep*DI*DCONV;
    const float* bc_l  = bc    + (size_t)dep*DI;
    const float* Wx_l  = Wx    + (size_t)dep*XDBL_N*DI;
    const float* Wdt_l = W_dt  + (size_t)dep*DI*DTR;
    const float* bdt_l = b_dt  + (size_t)dep*DI;
    const float* Alog_l= A_log + (size_t)dep*DI*DS;
    const float* Dp_l  = Dp    + (size_t)dep*DI;
    const float* Wout_l= W_out + (size_t)dep*DM*DI;

    // xz = LN(cur) @ W_in^T (fused; zeroes xdbl + scan flags)
    {
      dim3 grid((2*DI)/64, (L_TOK + 63)/64);
      lnxz_kernel<<<grid, 256, 0, stream>>>(cur, g, bb, Win_l, xz, xdbl, flags);
    }

    // xdbl = silu(conv(u)) @ Wx^T, split-K 12 (one k-step); exports uc
    {
      dim3 grid(1, (L_TOK + 63)/64, 12);
      cgemm_kernel<<<grid, 256, 0, stream>>>(xz, Wc_l, bc_l, Wx_l, xdbl, uc);
    }

    // fused selective scan
    {
      dim3 g1(NDG, NCHUNK);
      scan_fused<<<g1, 256, 0, stream>>>(uc, xdbl, xz, Wdt_l, bdt_l, Alog_l,
                                         Dp_l, cP, cS, flags, yy);
    }

    // cur += yy @ W_out^T : M=1569, N=192, K=384, split-K 4 (residual via atomic)
    {
      dim3 grid(DM/64, (L_TOK + 63)/64, 4);
      mgemm_kernel<<<grid, 256, 0, stream>>>(yy, DI, Wout_l, DI, cur, DM,
                                             L_TOK, DM, DI/4, 1);
    }
  }

  // final LN -> d_out
  ln_kernel<<<L_TOK, 64, 0, stream>>>(cur, (float*)d_out, fn_g, fn_b);
}

// Round 8
// 665.109 us; speedup vs baseline: 2.1180x; 2.1180x over previous
//
#include <hip/hip_runtime.h>
#include <hip/hip_bf16.h>
#include <math.h>

#define L_TOK 1569
#define DM 192
#define DI 384
#define DS 16
#define DTR 12
#define DCONV 4
#define XDBL_N (DTR + 2*DS)   // 44
#define DEPTH 8
#define NCHUNK 25
#define CLEN 64
#define NPATCH 1568
#define NDG 24                // d-groups (384/16)

typedef __attribute__((ext_vector_type(8))) short short8;
typedef __attribute__((ext_vector_type(4))) float f32x4;

__device__ __forceinline__ unsigned short f2bf(float f) {
  unsigned int u = __float_as_uint(f);
  u += 0x7FFFu + ((u >> 16) & 1u);   // round-to-nearest-even
  return (unsigned short)(u >> 16);
}

// ---------------------------------------------------------------------------
// im2col + cur init.
// ---------------------------------------------------------------------------
__global__ __launch_bounds__(256) void im2col_kernel(
    const float* __restrict__ x, const float* __restrict__ cls,
    const float* __restrict__ pb, const float* __restrict__ pos,
    float* __restrict__ px, float* __restrict__ curp) {
  int gid = blockIdx.x * 256 + threadIdx.x;
  const int initN = (L_TOK * DM) / 4;   // 75312 float4s
  if (gid < initN) {
    int e4 = gid * 4;
    int tok = e4 / DM;
    int col = e4 % DM;
    float4 pv = *(const float4*)(pos + e4);
    float4 av = (tok == 0) ? *(const float4*)(cls + col)
                           : *(const float4*)(pb + col);
    float4 o = {pv.x + av.x, pv.y + av.y, pv.z + av.z, pv.w + av.w};
    *(float4*)(curp + e4) = o;
  }
  if (gid >= NPATCH * 192) return;      // 192 float4 per patch
  int patch = gid / 192;
  int r = gid % 192;
  int c = r / 64;
  int p = (r >> 2) & 15;
  int q = (r & 3) * 4;
  int t = patch / 196, hw = patch % 196, hh = hw / 14, w = hw % 14;
  const float* src = x + ((size_t)(c*8 + t)*224 + hh*16 + p)*224 + w*16 + q;
  *(float4*)(px + (size_t)patch*768 + r*4) = *(const float4*)src;
}

// ---------------------------------------------------------------------------
// Final LayerNorm over 192 features. One wave per token, 3 elems/lane.
// ---------------------------------------------------------------------------
__global__ __launch_bounds__(64) void ln_kernel(
    const float* __restrict__ in, float* __restrict__ out,
    const float* __restrict__ g, const float* __restrict__ b) {
  int tokn = blockIdx.x;
  int lane = threadIdx.x;
  const float* row = in + (size_t)tokn*DM;
  float x0 = row[lane], x1 = row[lane+64], x2 = row[lane+128];
  float s = x0 + x1 + x2;
  float s2 = x0*x0 + x1*x1 + x2*x2;
#pragma unroll
  for (int off = 1; off < 64; off <<= 1) {
    s  += __shfl_xor(s,  off, 64);
    s2 += __shfl_xor(s2, off, 64);
  }
  float m = s * (1.0f/192.0f);
  float v = s2 * (1.0f/192.0f) - m*m;
  float rs = rsqrtf(v + 1e-5f);
  float* orow = out + (size_t)tokn*DM;
  orow[lane]     = (x0 - m)*rs*g[lane]     + b[lane];
  orow[lane+64]  = (x1 - m)*rs*g[lane+64]  + b[lane+64];
  orow[lane+128] = (x2 - m)*rs*g[lane+128] + b[lane+128];
}

// ---------------------------------------------------------------------------
// Fused LN + xz GEMM (K=192 fully in LDS, one barrier before 6 MFMA k-steps).
// blockIdx.x==0 blocks zero xdbl rows (atomic split-K cgemm downstream).
// ---------------------------------------------------------------------------
__global__ __launch_bounds__(256) void lnxz_kernel(
    const float* __restrict__ cur, const float* __restrict__ g,
    const float* __restrict__ b, const float* __restrict__ W,
    float* __restrict__ xz, float* __restrict__ xdbl_z) {
  __shared__ unsigned short As[64][200];
  __shared__ unsigned short Bs[64][200];
  __shared__ float gs[192], bs2[192];
  int tid = threadIdx.x;
  int m0 = blockIdx.y * 64, n0 = blockIdx.x * 64;
  int wave = tid >> 6, lane = tid & 63;
  int wr = wave >> 1, wc = wave & 1;
  int l15 = lane & 15, lk = (lane >> 4) * 8;

  for (int i = tid; i < 192; i += 256) { gs[i] = g[i]; bs2[i] = b[i]; }

  if (blockIdx.x == 0) {
    for (int i = tid; i < 64*11; i += 256) {
      int r = i / 11, q = i % 11;
      int row = m0 + r;
      if (row < L_TOK) {
        float4 z = {0.f,0.f,0.f,0.f};
        *(float4*)(xdbl_z + (size_t)row*XDBL_N + q*4) = z;
      }
    }
  }

  int r = tid >> 2, c0 = (tid & 3) * 48;
  float v[48];
  {
    int row = m0 + r;
    if (row < L_TOK) {
      const float* rp = cur + (size_t)row*DM + c0;
#pragma unroll
      for (int j = 0; j < 12; ++j) {
        float4 t4 = *(const float4*)(rp + j*4);
        v[j*4+0]=t4.x; v[j*4+1]=t4.y; v[j*4+2]=t4.z; v[j*4+3]=t4.w;
      }
    } else {
#pragma unroll
      for (int j = 0; j < 48; ++j) v[j] = 0.f;
    }
  }
  float s = 0.f, s2 = 0.f;
#pragma unroll
  for (int j = 0; j < 48; ++j) { s += v[j]; s2 += v[j]*v[j]; }
  s  += __shfl_xor(s, 1, 64); s2 += __shfl_xor(s2, 1, 64);
  s  += __shfl_xor(s, 2, 64); s2 += __shfl_xor(s2, 2, 64);
  float mu = s * (1.0f/192.0f);
  float var = s2 * (1.0f/192.0f) - mu*mu;
  float rsd = rsqrtf(var + 1e-5f);

  __syncthreads();   // gs/bs2 ready
#pragma unroll
  for (int j = 0; j < 48; ++j) {
    int k = c0 + j;
    As[r][k] = f2bf((v[j] - mu)*rsd*gs[k] + bs2[k]);
  }
  {
    const float* rp = W + (size_t)(n0 + r)*DM + c0;
#pragma unroll
    for (int j = 0; j < 12; ++j) {
      float4 t4 = *(const float4*)(rp + j*4);
      Bs[r][c0+j*4+0]=f2bf(t4.x); Bs[r][c0+j*4+1]=f2bf(t4.y);
      Bs[r][c0+j*4+2]=f2bf(t4.z); Bs[r][c0+j*4+3]=f2bf(t4.w);
    }
  }
  __syncthreads();

  f32x4 acc[2][2];
#pragma unroll
  for (int i = 0; i < 2; ++i)
#pragma unroll
    for (int j = 0; j < 2; ++j) acc[i][j] = (f32x4){0.f,0.f,0.f,0.f};

#pragma unroll
  for (int kk = 0; kk < 6; ++kk) {
    short8 af0 = *(const short8*)&As[wr*32      + l15][kk*32 + lk];
    short8 af1 = *(const short8*)&As[wr*32 + 16 + l15][kk*32 + lk];
    short8 bf0 = *(const short8*)&Bs[wc*32      + l15][kk*32 + lk];
    short8 bf1 = *(const short8*)&Bs[wc*32 + 16 + l15][kk*32 + lk];
    acc[0][0] = __builtin_amdgcn_mfma_f32_16x16x32_bf16(af0, bf0, acc[0][0], 0, 0, 0);
    acc[0][1] = __builtin_amdgcn_mfma_f32_16x16x32_bf16(af0, bf1, acc[0][1], 0, 0, 0);
    acc[1][0] = __builtin_amdgcn_mfma_f32_16x16x32_bf16(af1, bf0, acc[1][0], 0, 0, 0);
    acc[1][1] = __builtin_amdgcn_mfma_f32_16x16x32_bf16(af1, bf1, acc[1][1], 0, 0, 0);
  }

#pragma unroll
  for (int rr = 0; rr < 2; ++rr) {
#pragma unroll
    for (int cc = 0; cc < 2; ++cc) {
      int col = n0 + wc*32 + cc*16 + l15;
      int rowb = m0 + wr*32 + rr*16 + (lane >> 4)*4;
#pragma unroll
      for (int j = 0; j < 4; ++j) {
        int row = rowb + j;
        if (row < L_TOK) xz[(size_t)row*(2*DI) + col] = acc[rr][cc][j];
      }
    }
  }
}

// ---------------------------------------------------------------------------
// MFMA bf16 GEMM with split-K (patch embed + out projection).
// ---------------------------------------------------------------------------
__global__ __launch_bounds__(256) void mgemm_kernel(
    const float* __restrict__ A, int lda,
    const float* __restrict__ B, int ldb,
    float* __restrict__ C, int ldc,
    int M, int N, int ksl, int atomic) {
  __shared__ unsigned short As[64*40];
  __shared__ unsigned short Bs[64*40];
  int tid = threadIdx.x;
  int m0 = blockIdx.y * 64, n0 = blockIdx.x * 64;
  int kbase = blockIdx.z * ksl;
  int wave = tid >> 6, lane = tid & 63;
  int wr = wave >> 1, wc = wave & 1;
  int srow = tid >> 2;          // 0..63
  int skq  = (tid & 3) * 8;     // 0,8,16,24
  f32x4 acc[2][2];
#pragma unroll
  for (int i = 0; i < 2; ++i)
#pragma unroll
    for (int j = 0; j < 2; ++j) acc[i][j] = (f32x4){0.f,0.f,0.f,0.f};

  int am = m0 + srow;
  int bn = n0 + srow;
  bool a_ok = (am < M), b_ok = (bn < N);
  const float* ap = A + (size_t)am*lda + kbase + skq;
  const float* bp = B + (size_t)bn*ldb + kbase + skq;
  const float4 z4 = {0.f,0.f,0.f,0.f};
  int l15 = lane & 15, lk = (lane >> 4) * 8;

  int nt = ksl >> 5;
  float4 a0 = a_ok ? *(const float4*)(ap)     : z4;
  float4 a1 = a_ok ? *(const float4*)(ap + 4) : z4;
  float4 b0 = b_ok ? *(const float4*)(bp)     : z4;
  float4 b1 = b_ok ? *(const float4*)(bp + 4) : z4;

  for (int i = 0; i < nt; ++i) {
    {
      short8 pa, pb;
      pa[0]=f2bf(a0.x); pa[1]=f2bf(a0.y); pa[2]=f2bf(a0.z); pa[3]=f2bf(a0.w);
      pa[4]=f2bf(a1.x); pa[5]=f2bf(a1.y); pa[6]=f2bf(a1.z); pa[7]=f2bf(a1.w);
      pb[0]=f2bf(b0.x); pb[1]=f2bf(b0.y); pb[2]=f2bf(b0.z); pb[3]=f2bf(b0.w);
      pb[4]=f2bf(b1.x); pb[5]=f2bf(b1.y); pb[6]=f2bf(b1.z); pb[7]=f2bf(b1.w);
      *(short8*)&As[srow*40 + skq] = pa;
      *(short8*)&Bs[srow*40 + skq] = pb;
    }
    __syncthreads();
    bool pf = (i + 1 < nt);
    int k0n = (i + 1) << 5;
    a0 = (pf && a_ok) ? *(const float4*)(ap + k0n)     : z4;
    a1 = (pf && a_ok) ? *(const float4*)(ap + k0n + 4) : z4;
    b0 = (pf && b_ok) ? *(const float4*)(bp + k0n)     : z4;
    b1 = (pf && b_ok) ? *(const float4*)(bp + k0n + 4) : z4;

    short8 af0 = *(const short8*)&As[(wr*32      + l15)*40 + lk];
    short8 af1 = *(const short8*)&As[(wr*32 + 16 + l15)*40 + lk];
    short8 bf0 = *(const short8*)&Bs[(wc*32      + l15)*40 + lk];
    short8 bf1 = *(const short8*)&Bs[(wc*32 + 16 + l15)*40 + lk];
    acc[0][0] = __builtin_amdgcn_mfma_f32_16x16x32_bf16(af0, bf0, acc[0][0], 0, 0, 0);
    acc[0][1] = __builtin_amdgcn_mfma_f32_16x16x32_bf16(af0, bf1, acc[0][1], 0, 0, 0);
    acc[1][0] = __builtin_amdgcn_mfma_f32_16x16x32_bf16(af1, bf0, acc[1][0], 0, 0, 0);
    acc[1][1] = __builtin_amdgcn_mfma_f32_16x16x32_bf16(af1, bf1, acc[1][1], 0, 0, 0);
    __syncthreads();
  }

#pragma unroll
  for (int r = 0; r < 2; ++r) {
#pragma unroll
    for (int c = 0; c < 2; ++c) {
      int col = n0 + wc*32 + c*16 + l15;
      if (col >= N) continue;
      int rowb = m0 + wr*32 + r*16 + (lane >> 4)*4;
#pragma unroll
      for (int j = 0; j < 4; ++j) {
        int row = rowb + j;
        if (row >= M) continue;
        float v = acc[r][c][j];
        float* cp = C + (size_t)row*ldc + col;
        if (atomic) atomicAdd(cp, v);
        else        *cp = v;
      }
    }
  }
}

// ---------------------------------------------------------------------------
// xdbl GEMM, conv+SiLU fused in A-staging; split-K 12 (ksl=32, one k-step).
// Also exports u = silu(conv(xz)) to uc (fp32) for the scan.
// grid = (1, 25, 12). C zero-initialized by lnxz.
// ---------------------------------------------------------------------------
__global__ __launch_bounds__(256) void cgemm_kernel(
    const float* __restrict__ xz,
    const float* __restrict__ Wc, const float* __restrict__ bc,
    const float* __restrict__ B, float* __restrict__ C,
    float* __restrict__ uc) {
  __shared__ unsigned short As[64*40];
  __shared__ unsigned short Bs[64*40];
  __shared__ float wcs[32][4];
  __shared__ float bcs[32];
  const int M = L_TOK, N = XDBL_N;
  int tid = threadIdx.x;
  int m0 = blockIdx.y * 64;
  int kbase = blockIdx.z * 32;
  int wave = tid >> 6, lane = tid & 63;
  int wr = wave >> 1, wcq = wave & 1;
  int srow = tid >> 2;
  int skq  = (tid & 3) * 8;
  if (tid < 32) {
    *(float4*)wcs[tid] = *(const float4*)(Wc + (size_t)(kbase + tid)*4);
    bcs[tid] = bc[kbase + tid];
  }

  int t = m0 + srow;
  bool a_ok = (t < M);
  bool b_ok = (srow < N);
  const float* bp = B + (size_t)srow*DI + kbase + skq;
  const float4 z4 = {0.f,0.f,0.f,0.f};
  int l15 = lane & 15, lk = (lane >> 4) * 8;
  int cg = kbase + skq;

  float tap[4][8];
#pragma unroll
  for (int j = 0; j < 4; ++j) {
    int ts = t - 3 + j;
    float4 v0 = z4, v1 = z4;
    if (a_ok && ts >= 0) {
      v0 = *(const float4*)(xz + (size_t)ts*(2*DI) + cg);
      v1 = *(const float4*)(xz + (size_t)ts*(2*DI) + cg + 4);
    }
    tap[j][0]=v0.x; tap[j][1]=v0.y; tap[j][2]=v0.z; tap[j][3]=v0.w;
    tap[j][4]=v1.x; tap[j][5]=v1.y; tap[j][6]=v1.z; tap[j][7]=v1.w;
  }
  float4 bv0 = b_ok ? *(const float4*)(bp)     : z4;
  float4 bv1 = b_ok ? *(const float4*)(bp + 4) : z4;
  __syncthreads();   // wcs/bcs ready

  float uv[8];
  short8 pa, pb;
#pragma unroll
  for (int c = 0; c < 8; ++c) {
    float u = bcs[skq + c];
#pragma unroll
    for (int j = 0; j < 4; ++j) u = fmaf(tap[j][c], wcs[skq + c][j], u);
    u = u / (1.0f + expf(-u));
    uv[c] = u;
    pa[c] = (short)f2bf(u);
  }
  if (a_ok) {
    float4 o0 = {uv[0], uv[1], uv[2], uv[3]};
    float4 o1 = {uv[4], uv[5], uv[6], uv[7]};
    *(float4*)(uc + (size_t)t*DI + cg)     = o0;
    *(float4*)(uc + (size_t)t*DI + cg + 4) = o1;
  }
  pb[0]=f2bf(bv0.x); pb[1]=f2bf(bv0.y); pb[2]=f2bf(bv0.z); pb[3]=f2bf(bv0.w);
  pb[4]=f2bf(bv1.x); pb[5]=f2bf(bv1.y); pb[6]=f2bf(bv1.z); pb[7]=f2bf(bv1.w);
  *(short8*)&As[srow*40 + skq] = pa;
  *(short8*)&Bs[srow*40 + skq] = pb;
  __syncthreads();

  f32x4 acc[2][2];
#pragma unroll
  for (int i = 0; i < 2; ++i)
#pragma unroll
    for (int j = 0; j < 2; ++j) acc[i][j] = (f32x4){0.f,0.f,0.f,0.f};
  short8 af0 = *(const short8*)&As[(wr*32      + l15)*40 + lk];
  short8 af1 = *(const short8*)&As[(wr*32 + 16 + l15)*40 + lk];
  short8 bf0 = *(const short8*)&Bs[(wcq*32      + l15)*40 + lk];
  short8 bf1 = *(const short8*)&Bs[(wcq*32 + 16 + l15)*40 + lk];
  acc[0][0] = __builtin_amdgcn_mfma_f32_16x16x32_bf16(af0, bf0, acc[0][0], 0, 0, 0);
  acc[0][1] = __builtin_amdgcn_mfma_f32_16x16x32_bf16(af0, bf1, acc[0][1], 0, 0, 0);
  acc[1][0] = __builtin_amdgcn_mfma_f32_16x16x32_bf16(af1, bf0, acc[1][0], 0, 0, 0);
  acc[1][1] = __builtin_amdgcn_mfma_f32_16x16x32_bf16(af1, bf1, acc[1][1], 0, 0, 0);

#pragma unroll
  for (int r = 0; r < 2; ++r) {
#pragma unroll
    for (int c = 0; c < 2; ++c) {
      int col = wcq*32 + c*16 + l15;
      if (col >= N) continue;
      int rowb = m0 + wr*32 + r*16 + (lane >> 4)*4;
#pragma unroll
      for (int j = 0; j < 4; ++j) {
        int row = rowb + j;
        if (row >= M) continue;
        atomicAdd(C + (size_t)row*XDBL_N + col, acc[r][c][j]);
      }
    }
  }
}

// ---------------------------------------------------------------------------
// Selective scan phase 1: per-chunk local scan from zero state.
// Consumes uc (precomputed u); computes delta and exports it to dlt.
// grid = (NDG, NCHUNK), 256 thr = 16d x 16n.
// ---------------------------------------------------------------------------
__global__ __launch_bounds__(256) void scan_p1(
    const float* __restrict__ uc, const float* __restrict__ xdbl,
    const float* __restrict__ W_dt, const float* __restrict__ b_dt,
    const float* __restrict__ A_log,
    float* __restrict__ cP, float* __restrict__ cS,
    float* __restrict__ dlt) {
  __shared__ float us[CLEN][16], ds[CLEN][16], bs[CLEN][16];
  __shared__ float xd12[CLEN][12], wdt[16][12], bds[16];
  int tid = threadIdx.x;
  int dl = tid >> 4, n = tid & 15;
  int d0 = blockIdx.x * 16;
  int t0 = blockIdx.y * CLEN;
  int nt = min(CLEN, L_TOK - t0);

  for (int i = tid; i < CLEN*16; i += 256) {
    int tt = i >> 4, dd = i & 15;
    int t = t0 + tt;
    us[tt][dd] = (t < L_TOK) ? uc[(size_t)t*DI + d0 + dd] : 0.0f;
  }
  for (int i = tid; i < CLEN*28; i += 256) {
    int tt = i / 28, c = i % 28;
    int t = t0 + tt;
    float v = (t < L_TOK) ? xdbl[(size_t)t*XDBL_N + c] : 0.0f;
    if (c < 12) xd12[tt][c] = v;
    else bs[tt][c-12] = v;
  }
  if (tid < 192) wdt[tid/12][tid%12] = W_dt[(d0 + tid/12)*DTR + tid%12];
  if (tid < 16)  bds[tid] = b_dt[d0+tid];
  __syncthreads();
  for (int i = tid; i < CLEN*16; i += 256) {
    int tt = i >> 4, dd = i & 15;
    float v = bds[dd];
#pragma unroll
    for (int r = 0; r < 12; ++r) v = fmaf(xd12[tt][r], wdt[dd][r], v);
    v = (v > 20.0f) ? v : log1pf(expf(v));
    ds[tt][dd] = v;
    int t = t0 + tt;
    if (t < L_TOK) dlt[(size_t)t*DI + d0 + dd] = v;
  }
  __syncthreads();

  int d = d0 + dl;
  float a2 = -expf(A_log[d*DS + n]) * 1.44269504088896340736f;
  float s = 0.0f, P = 1.0f;
  for (int tt = 0; tt < nt; ++tt) {
    float dv = ds[tt][dl];
    float dA = exp2f(dv * a2);
    s = fmaf(dA, s, dv * bs[tt][n] * us[tt][dl]);
    P *= dA;
  }
  int o = (blockIdx.y * DI + d) * DS + n;
  cP[o] = P;
  cS[o] = s;
}

// ---------------------------------------------------------------------------
// Selective scan phase 3: carry-in from cP/cS (serial per-thread combine over
// preceding chunks), then re-scan and emit y (u*Dp + silu(z) gate fused).
// ---------------------------------------------------------------------------
__global__ __launch_bounds__(256) void scan_p3(
    const float* __restrict__ uc, const float* __restrict__ dlt,
    const float* __restrict__ xdbl, const float* __restrict__ xz,
    const float* __restrict__ A_log, const float* __restrict__ Dp,
    const float* __restrict__ cP, const float* __restrict__ cS,
    float* __restrict__ yy) {
  __shared__ float us[CLEN][16], ds[CLEN][16], bs[CLEN][16];
  __shared__ float cs[CLEN][16], zs[CLEN][16];
  int tid = threadIdx.x;
  int dl = tid >> 4, n = tid & 15;
  int d0 = blockIdx.x * 16;
  int cidx = blockIdx.y;
  int t0 = cidx * CLEN;
  int nt = min(CLEN, L_TOK - t0);
  int d = d0 + dl;

  // carry-in scan over preceding chunks (no staging dependency)
  float s = 0.0f;
  {
    int oo = d * DS + n;
    for (int c2 = 0; c2 < cidx; ++c2) {
      s = fmaf(cP[(size_t)c2*(DI*DS) + oo], s, cS[(size_t)c2*(DI*DS) + oo]);
    }
  }

  for (int i = tid; i < CLEN*16; i += 256) {
    int tt = i >> 4, dd = i & 15;
    int t = t0 + tt;
    bool ok = (t < L_TOK);
    us[tt][dd] = ok ? uc[(size_t)t*DI + d0 + dd] : 0.0f;
    ds[tt][dd] = ok ? dlt[(size_t)t*DI + d0 + dd] : 0.0f;
    zs[tt][dd] = ok ? xz[(size_t)t*(2*DI) + DI + d0 + dd] : 0.0f;
  }
  for (int i = tid; i < CLEN*32; i += 256) {
    int tt = i >> 5, c = i & 31;
    int t = t0 + tt;
    float v = (t < L_TOK) ? xdbl[(size_t)t*XDBL_N + 12 + c] : 0.0f;
    if (c < 16) bs[tt][c] = v;
    else cs[tt][c-16] = v;
  }
  __syncthreads();

  float a2 = -expf(A_log[d*DS + n]) * 1.44269504088896340736f;
  float dpv = Dp[d];
  for (int tt = 0; tt < nt; ++tt) {
    float dv = ds[tt][dl], uu = us[tt][dl];
    float dA = exp2f(dv * a2);
    s = fmaf(dA, s, dv * bs[tt][n] * uu);
    float p = s * cs[tt][n];
    p += __shfl_xor(p, 1, 64);
    p += __shfl_xor(p, 2, 64);
    p += __shfl_xor(p, 4, 64);
    p += __shfl_xor(p, 8, 64);
    if (n == 0) {
      float z = zs[tt][dl];
      float y = fmaf(uu, dpv, p);
      y *= z / (1.0f + expf(-z));
      yy[(size_t)(t0 + tt)*DI + d] = y;
    }
  }
}

// ---------------------------------------------------------------------------
extern "C" void kernel_launch(void* const* d_in, const int* in_sizes, int n_in,
                              void* d_out, int out_size, void* d_ws, size_t ws_size,
                              hipStream_t stream) {
  const float* x       = (const float*)d_in[0];
  const float* patch_w = (const float*)d_in[1];
  const float* patch_b = (const float*)d_in[2];
  const float* cls_tok = (const float*)d_in[3];
  const float* pos_emb = (const float*)d_in[4];
  const float* ln_g    = (const float*)d_in[5];
  const float* ln_b    = (const float*)d_in[6];
  const float* W_in    = (const float*)d_in[7];
  const float* Wc      = (const float*)d_in[8];
  const float* bc      = (const float*)d_in[9];
  const float* Wx      = (const float*)d_in[10];
  const float* W_dt    = (const float*)d_in[11];
  const float* b_dt    = (const float*)d_in[12];
  const float* A_log   = (const float*)d_in[13];
  const float* Dp      = (const float*)d_in[14];
  const float* W_out   = (const float*)d_in[15];
  const float* fn_g    = (const float*)d_in[16];
  const float* fn_b    = (const float*)d_in[17];

  float* ws = (float*)d_ws;
  float* cur   = ws;                       // 1569*192
  float* xz    = cur   + L_TOK*DM;         // 1569*768 (aliases px)
  float* xdbl  = xz    + L_TOK*2*DI;       // 1569*44
  float* yy    = xdbl  + L_TOK*XDBL_N;     // 1569*384
  float* uc    = yy    + L_TOK*DI;         // 1569*384
  float* dlt   = uc    + L_TOK*DI;         // 1569*384
  float* cP    = dlt   + L_TOK*DI;         // 25*6144
  float* cS    = cP    + NCHUNK*DI*DS;
  float* px    = xz;                       // im2col buffer, dead before layer 0's xz

  // im2col + cur init (pos + bias/cls)
  im2col_kernel<<<(NPATCH*192 + 255)/256, 256, 0, stream>>>(
      x, cls_tok, patch_b, pos_emb, px, cur);
  // patch GEMM: cur[1..] += px @ patch_w^T, M=1568, N=192, K=768, split-K 4
  {
    dim3 grid(DM/64, (NPATCH + 63)/64, 4);
    mgemm_kernel<<<grid, 256, 0, stream>>>(px, 768, patch_w, 768, cur + DM, DM,
                                           NPATCH, DM, 768/4, 1);
  }

  for (int dep = 0; dep < DEPTH; ++dep) {
    const float* g     = ln_g  + dep*DM;
    const float* bb    = ln_b  + dep*DM;
    const float* Win_l = W_in  + (size_t)dep*2*DI*DM;
    const float* Wc_l  = Wc    + (size_t)dep*DI*DCONV;
    const float* bc_l  = bc    + (size_t)dep*DI;
    const float* Wx_l  = Wx    + (size_t)dep*XDBL_N*DI;
    const float* Wdt_l = W_dt  + (size_t)dep*DI*DTR;
    const float* bdt_l = b_dt  + (size_t)dep*DI;
    const float* Alog_l= A_log + (size_t)dep*DI*DS;
    const float* Dp_l  = Dp    + (size_t)dep*DI;
    const float* Wout_l= W_out + (size_t)dep*DM*DI;

    // xz = LN(cur) @ W_in^T (fused; zeroes xdbl)
    {
      dim3 grid((2*DI)/64, (L_TOK + 63)/64);
      lnxz_kernel<<<grid, 256, 0, stream>>>(cur, g, bb, Win_l, xz, xdbl);
    }

    // xdbl = silu(conv(u)) @ Wx^T, split-K 12 (one k-step); exports uc
    {
      dim3 grid(1, (L_TOK + 63)/64, 12);
      cgemm_kernel<<<grid, 256, 0, stream>>>(xz, Wc_l, bc_l, Wx_l, xdbl, uc);
    }

    // selective scan (split, no inter-block sync; p1 exports delta)
    {
      dim3 g1(NDG, NCHUNK);
      scan_p1<<<g1, 256, 0, stream>>>(uc, xdbl, Wdt_l, bdt_l, Alog_l, cP, cS, dlt);
      scan_p3<<<g1, 256, 0, stream>>>(uc, dlt, xdbl, xz, Alog_l, Dp_l, cP, cS, yy);
    }

    // cur += yy @ W_out^T : M=1569, N=192, K=384, split-K 4 (residual via atomic)
    {
      dim3 grid(DM/64, (L_TOK + 63)/64, 4);
      mgemm_kernel<<<grid, 256, 0, stream>>>(yy, DI, Wout_l, DI, cur, DM,
                                             L_TOK, DM, DI/4, 1);
    }
  }

  // final LN -> d_out
  ln_kernel<<<L_TOK, 64, 0, stream>>>(cur, (float*)d_out, fn_g, fn_b);
}